// Round 15
// baseline (284.240 us; speedup 1.0000x reference)
//
#include <hip/hip_runtime.h>
#include <hip/hip_fp16.h>

#define D 64          // hidden/output feature dim
#define NBUCK 512     // dst buckets (dst>>8), 391 used
#define EPB 8192      // edges per k_bin block (256 thr, 64 KB stage)
#define BDST 32       // dst bucket-count blocks (private slices)
#define NSH 128       // src-hist blocks in merged kernel (2 halves x 64 chunks)
#define BSTAGE 8192   // k_bsort LDS stage capacity (edges); avg bucket ~4090

typedef __attribute__((ext_vector_type(8))) short short8;   // 8 bf16 (4 VGPRs)
typedef __attribute__((ext_vector_type(4))) float floatx4;  // 4 fp32 acc

// ---------------------------------------------------------------------------
// dst bucket counts -> private slices (atomic-free output; scanB folds).
// ---------------------------------------------------------------------------
__global__ __launch_bounds__(1024) void k_histdst(const int* __restrict__ dst,
                                                  int* __restrict__ bucket_cnt_part,
                                                  int E) {
    __shared__ int hb[NBUCK];
    int tid = threadIdx.x;
    const int E4 = E >> 2;
    for (int i = tid; i < NBUCK; i += 1024) hb[i] = 0;
    __syncthreads();
    const int4* d4 = (const int4*)dst;
    int stride = BDST * 1024;
    for (int i = blockIdx.x * 1024 + tid; i < E4; i += stride) {
        int4 v = d4[i];
        atomicAdd(&hb[v.x >> 8], 1);
        atomicAdd(&hb[v.y >> 8], 1);
        atomicAdd(&hb[v.z >> 8], 1);
        atomicAdd(&hb[v.w >> 8], 1);
    }
    if (blockIdx.x == 0) {
        int e = E4 * 4 + tid;
        if (e < E) atomicAdd(&hb[dst[e] >> 8], 1);
    }
    __syncthreads();
    int* my = bucket_cnt_part + blockIdx.x * NBUCK;
    for (int i = tid; i < NBUCK; i += 1024) my[i] = hb[i];
}

// ---- fold BDST bucket-count slices + exclusive scan + sentinels ----
__global__ __launch_bounds__(512) void k_scanB(const int* __restrict__ bucket_cnt_part,
                                               int* __restrict__ bucket_ptr,
                                               int* __restrict__ row_ptr, int N, int E) {
    __shared__ int s[512];
    int tid = threadIdx.x;
    int v = 0;
#pragma unroll
    for (int b = 0; b < BDST; ++b) v += bucket_cnt_part[b * NBUCK + tid];
    s[tid] = v;
    __syncthreads();
    for (int off = 1; off < 512; off <<= 1) {
        int add = (tid >= off) ? s[tid - off] : 0;
        __syncthreads();
        s[tid] += add;
        __syncthreads();
    }
    bucket_ptr[tid] = s[tid] - v;          // exclusive
    if (tid == 511) bucket_ptr[512] = s[511];
    if (tid == 0) row_ptr[N] = E;          // sentinel for k_agg's rp[i+1]
}

// ---------------------------------------------------------------------------
// MERGED: binned CSR build (blocks < NBK) + src out-degree histogram
// (blocks >= NBK). The two roles run CONCURRENTLY on disjoint CUs (196+128
// blocks @ 2/CU = 162 CUs), hiding the src-hist time entirely under bin.
// LDS is a 73 KB union: bin's 64 KB stage doubles as the hist's packed
// byte-lane counters (half of N per block, 2 halves x 64 edge-chunks).
// No global atomics (R8 lesson). EPB 8192: 2x bucket-run length, half the
// cursor atomics vs EPB 4096.
// ---------------------------------------------------------------------------
__global__ __launch_bounds__(256) void k_binhist(const int* __restrict__ src,
                                                 const int* __restrict__ dst,
                                                 const int* __restrict__ bucket_ptr,
                                                 int* __restrict__ bucket_cursor,
                                                 unsigned long long* __restrict__ binned,
                                                 unsigned* __restrict__ hstage,
                                                 int E, int N, int NBK) {
    __shared__ unsigned long long stage[EPB];   // 64 KB (hist reuses as hw)
    __shared__ int cnt[NBUCK];
    __shared__ int bloc[NBUCK];
    __shared__ int lcur[NBUCK];
    __shared__ int gbase[NBUCK];
    __shared__ int ss[256];
    int tid = threadIdx.x;
    const int E4 = E >> 2;

    if ((int)blockIdx.x >= NBK) {
        // ---- src out-degree role: packed byte-lane LDS counters ----
        unsigned* hw = (unsigned*)stage;        // 16384 words available
        int b  = blockIdx.x - NBK;              // 0..NSH-1
        int hb = b >> 6;                        // half id (0/1)
        int c  = b & 63;                        // edge-chunk id
        int NH = (N + 1) >> 1;
        int lo = hb * NH;
        int hi = min(lo + NH, N);
        int wlen2 = (NH + 3) >> 2;              // <= 16384
        for (int i = tid; i < wlen2; i += 256) hw[i] = 0;
        __syncthreads();
        const int4* s4 = (const int4*)src;
        for (int i = c * 256 + tid; i < E4; i += 64 * 256) {
            int4 v = s4[i];
            if (v.x >= lo && v.x < hi) { int l = v.x - lo; atomicAdd(&hw[l >> 2], 1u << ((l & 3) * 8)); }
            if (v.y >= lo && v.y < hi) { int l = v.y - lo; atomicAdd(&hw[l >> 2], 1u << ((l & 3) * 8)); }
            if (v.z >= lo && v.z < hi) { int l = v.z - lo; atomicAdd(&hw[l >> 2], 1u << ((l & 3) * 8)); }
            if (v.w >= lo && v.w < hi) { int l = v.w - lo; atomicAdd(&hw[l >> 2], 1u << ((l & 3) * 8)); }
        }
        if (c == 0) {
            int e = E4 * 4 + tid;
            if (e < E) {
                int v = src[e];
                if (v >= lo && v < hi) { int l = v - lo; atomicAdd(&hw[l >> 2], 1u << ((l & 3) * 8)); }
            }
        }
        __syncthreads();
        unsigned* my = hstage + (long long)b * wlen2;
        for (int i = tid; i < wlen2; i += 256) my[i] = hw[i];   // coalesced
        return;
    }

    // ---- bin role ----
    int start = blockIdx.x * EPB;
    int nloc = min(EPB, E - start);

    for (int i = tid; i < NBUCK; i += 256) cnt[i] = 0;
    __syncthreads();

#pragma unroll
    for (int r = 0; r < EPB / 256; ++r) {
        int idx = start + r * 256 + tid;
        if (idx < E) atomicAdd(&cnt[dst[idx] >> 8], 1);
    }
    __syncthreads();

    int a = cnt[2 * tid], b = cnt[2 * tid + 1];
    ss[tid] = a + b;
    __syncthreads();
    for (int off = 1; off < 256; off <<= 1) {
        int add = (tid >= off) ? ss[tid - off] : 0;
        __syncthreads();
        ss[tid] += add;
        __syncthreads();
    }
    int excl = ss[tid] - (a + b);
    bloc[2 * tid] = excl;           lcur[2 * tid] = excl;
    bloc[2 * tid + 1] = excl + a;   lcur[2 * tid + 1] = excl + a;
    __syncthreads();

    for (int bk = tid; bk < NBUCK; bk += 256) {
        int c = cnt[bk];
        gbase[bk] = c ? (atomicAdd(&bucket_cursor[bk], c) + bucket_ptr[bk]) : 0;
    }
    __syncthreads();

#pragma unroll
    for (int r = 0; r < EPB / 256; ++r) {
        int idx = start + r * 256 + tid;
        if (idx < E) {
            int d = dst[idx];
            int p = atomicAdd(&lcur[d >> 8], 1);
            stage[p] = ((unsigned long long)(unsigned)d << 32) | (unsigned)src[idx];
        }
    }
    __syncthreads();

#pragma unroll
    for (int r = 0; r < EPB / 256; ++r) {
        int i = r * 256 + tid;
        if (i < nloc) {
            unsigned long long e = stage[i];
            int bk = (int)(e >> 40);
            binned[gbase[bk] + (i - bloc[bk])] = e;
        }
    }
}

// ---------------------------------------------------------------------------
// Per-bucket sort, one-pass LDS staging; derives row_ptr + both norms.
// norm_src folds the NSH half-range byte-lane histogram slices (64 per half).
// ---------------------------------------------------------------------------
__global__ __launch_bounds__(256) void k_bsort(const unsigned long long* __restrict__ binned,
                                               const int* __restrict__ bucket_ptr,
                                               const unsigned* __restrict__ hstage,
                                               int* __restrict__ csr,
                                               int* __restrict__ row_ptr,
                                               float* __restrict__ norm_src,
                                               float* __restrict__ norm_dst, int N) {
    __shared__ unsigned long long est[BSTAGE];
    __shared__ int cnt256[256];
    __shared__ int ss[256];
    __shared__ int cur[256];
    int b = blockIdx.x;
    int n0 = b << 8;
    int tid = threadIdx.x;
    int base = bucket_ptr[b];
    int ctot = bucket_ptr[b + 1] - base;
    bool fits = (ctot <= BSTAGE);

    cnt256[tid] = 0;
    __syncthreads();

    if (fits) {
        for (int k = tid; k < ctot; k += 256) {
            unsigned long long e = binned[base + k];   // single global read
            est[k] = e;
            atomicAdd(&cnt256[(int)(e >> 32) - n0], 1);
        }
    } else {
        for (int k = tid; k < ctot; k += 256)
            atomicAdd(&cnt256[(int)(binned[base + k] >> 32) - n0], 1);
    }
    __syncthreads();

    int v = cnt256[tid];
    ss[tid] = v;
    __syncthreads();
    for (int off = 1; off < 256; off <<= 1) {
        int add = (tid >= off) ? ss[tid - off] : 0;
        __syncthreads();
        ss[tid] += add;
        __syncthreads();
    }
    int excl = ss[tid] - v;
    int node = n0 + tid;
    if (node < N) {
        row_ptr[node] = base + excl;
        norm_dst[node] = rsqrtf((float)v + 1.0f);            // +1 self loop
        int NH = (N + 1) >> 1;
        int wlen2 = (NH + 3) >> 2;
        int hb = (node >= NH) ? 1 : 0;
        int local = node - hb * NH;
        unsigned sh = (unsigned)(local & 3) * 8u;
        const unsigned* q = hstage + (long long)(hb * 64) * wlen2 + (local >> 2);
        int od = 0;
#pragma unroll 8
        for (int p = 0; p < 64; ++p) {
            od += (int)((*q >> sh) & 0xffu);
            q += wlen2;
        }
        norm_src[node] = rsqrtf((float)od + 1.0f);
    }
    cur[tid] = base + excl;
    __syncthreads();

    if (fits) {
        for (int k = tid; k < ctot; k += 256) {
            unsigned long long e = est[k];
            int p = atomicAdd(&cur[(int)(e >> 32) - n0], 1);
            csr[p] = (int)(e & 0xffffffffu);
        }
    } else {
        for (int k = tid; k < ctot; k += 256) {
            unsigned long long e = binned[base + k];
            int p = atomicAdd(&cur[(int)(e >> 32) - n0], 1);
            csr[p] = (int)(e & 0xffffffffu);
        }
    }
}

// ---------------------------------------------------------------------------
// MFMA dense layer via split-bf16 (verbatim, interleaved t layout)
// ---------------------------------------------------------------------------
template <int K>
__global__ __launch_bounds__(256) void k_gemm_mfma(const float* __restrict__ hsrc,
                                                   const float* __restrict__ W,   // [K,64] row-major
                                                   const float* __restrict__ norm_src,
                                                   __half* __restrict__ t, int N) {
    constexpr int NKI = K / 32;
    __shared__ short Whi[NKI * 2048];
    __shared__ short Wlo[NKI * 2048];
    int tid = threadIdx.x;

    for (int f = tid; f < K * 64; f += 256) {
        int n  = f & 15;
        int j  = (f >> 4) & 7;
        int q  = (f >> 7) & 3;
        int ct = (f >> 9) & 3;
        int ki = f >> 11;
        int k = ki * 32 + q * 8 + j;
        int c = ct * 16 + n;
        float w = W[k * 64 + c];
        unsigned u = __float_as_uint(w);
        float l = w - __uint_as_float(u & 0xffff0000u);
        int idx = (((ki * 4 + ct) * 16 + n) * 4 + q) * 8 + j;
        Whi[idx] = (short)(u >> 16);
        Wlo[idx] = (short)(__float_as_uint(l) >> 16);
    }
    __syncthreads();

    int wave = tid >> 6, lane = tid & 63;
    int q = lane >> 4, n = lane & 15;
    int r0 = blockIdx.x * 64 + wave * 16;
    int rowc = min(r0 + n, N - 1);

    floatx4 acc[4] = {{0.f,0.f,0.f,0.f},{0.f,0.f,0.f,0.f},
                      {0.f,0.f,0.f,0.f},{0.f,0.f,0.f,0.f}};

    for (int ki = 0; ki < NKI; ++ki) {
        const float* ap = hsrc + (long long)rowc * K + ki * 32 + q * 8;
        float4 a0 = *(const float4*)ap;
        float4 a1 = *(const float4*)(ap + 4);
        float av[8] = {a0.x, a0.y, a0.z, a0.w, a1.x, a1.y, a1.z, a1.w};
        short8 ahi, alo;
#pragma unroll
        for (int j = 0; j < 8; ++j) {
            unsigned u = __float_as_uint(av[j]);
            float l = av[j] - __uint_as_float(u & 0xffff0000u);
            ahi[j] = (short)(u >> 16);
            alo[j] = (short)(__float_as_uint(l) >> 16);
        }
#pragma unroll
        for (int ct = 0; ct < 4; ++ct) {
            int bidx = (((ki * 4 + ct) * 16 + n) * 4 + q) * 8;
            short8 bhi = *(const short8*)&Whi[bidx];
            short8 blo = *(const short8*)&Wlo[bidx];
            acc[ct] = __builtin_amdgcn_mfma_f32_16x16x32_bf16(ahi, bhi, acc[ct], 0, 0, 0);
            acc[ct] = __builtin_amdgcn_mfma_f32_16x16x32_bf16(ahi, blo, acc[ct], 0, 0, 0);
            acc[ct] = __builtin_amdgcn_mfma_f32_16x16x32_bf16(alo, bhi, acc[ct], 0, 0, 0);
        }
    }

#pragma unroll
    for (int reg = 0; reg < 4; ++reg) {
        int orow = r0 + q * 4 + reg;
        if (orow < N) {
            float nrm = norm_src[orow];
#pragma unroll
            for (int ct = 0; ct < 4; ++ct)
                t[(long long)orow * 64 + ct * 16 + n] = __float2half(acc[ct][reg] * nrm);
        }
    }
}

// ---------------------------------------------------------------------------
// gather-aggregate (R9-verified 8-deep form; R12 showed 16-deep is null:
// the kernel sits at the ~4.7 TB/s line-touch wall, not MLP-depth-bound).
// ---------------------------------------------------------------------------
__global__ __launch_bounds__(256) void k_agg(const int* __restrict__ row_ptr,
                                             const int* __restrict__ csr,
                                             const __half* __restrict__ t,
                                             const float* __restrict__ norm_dst,
                                             const float* __restrict__ bias,
                                             float* __restrict__ out, int N, int do_relu) {
    int tid = threadIdx.x;
    int half_id = tid >> 5;
    int lane = tid & 31;
    int i = blockIdx.x * 8 + half_id;
    if (i >= N) return;
    const __half2* t2 = (const __half2*)t;
    int start = row_ptr[i];
    int c = row_ptr[i + 1] - start;

    float2 sf = __half22float2(t2[i * 32 + lane]);
    float ax = sf.x, ay = sf.y;

    int j = 0;
    int pre = min(c, (4 - (start & 3)) & 3);   // align csr pointer to 16B
    for (; j < pre; ++j) {
        float2 f = __half22float2(t2[csr[start + j] * 32 + lane]);
        ax += f.x; ay += f.y;
    }
    for (; j + 8 <= c; j += 8) {
        int4 s4 = *(const int4*)&csr[start + j];
        int4 s5 = *(const int4*)&csr[start + j + 4];
        float2 f0 = __half22float2(t2[s4.x * 32 + lane]);
        float2 f1 = __half22float2(t2[s4.y * 32 + lane]);
        float2 f2 = __half22float2(t2[s4.z * 32 + lane]);
        float2 f3 = __half22float2(t2[s4.w * 32 + lane]);
        float2 f4 = __half22float2(t2[s5.x * 32 + lane]);
        float2 f5 = __half22float2(t2[s5.y * 32 + lane]);
        float2 f6 = __half22float2(t2[s5.z * 32 + lane]);
        float2 f7 = __half22float2(t2[s5.w * 32 + lane]);
        ax += ((f0.x + f1.x) + (f2.x + f3.x)) + ((f4.x + f5.x) + (f6.x + f7.x));
        ay += ((f0.y + f1.y) + (f2.y + f3.y)) + ((f4.y + f5.y) + (f6.y + f7.y));
    }
    for (; j + 4 <= c; j += 4) {
        int4 s4 = *(const int4*)&csr[start + j];
        float2 f0 = __half22float2(t2[s4.x * 32 + lane]);
        float2 f1 = __half22float2(t2[s4.y * 32 + lane]);
        float2 f2 = __half22float2(t2[s4.z * 32 + lane]);
        float2 f3 = __half22float2(t2[s4.w * 32 + lane]);
        ax += (f0.x + f1.x) + (f2.x + f3.x);
        ay += (f0.y + f1.y) + (f2.y + f3.y);
    }
    for (; j < c; ++j) {
        float2 f = __half22float2(t2[csr[start + j] * 32 + lane]);
        ax += f.x; ay += f.y;
    }

    float nrm = norm_dst[i];
    float2 bb = ((const float2*)bias)[lane];
    float vx = fmaf(ax, nrm, bb.x);
    float vy = fmaf(ay, nrm, bb.y);
    if (do_relu) { vx = fmaxf(vx, 0.f); vy = fmaxf(vy, 0.f); }
    float2 o; o.x = vx; o.y = vy;
    ((float2*)out)[i * 32 + lane] = o;
}

extern "C" void kernel_launch(void* const* d_in, const int* in_sizes, int n_in,
                              void* d_out, int out_size, void* d_ws, size_t ws_size,
                              hipStream_t stream) {
    const float* x   = (const float*)d_in[0];
    const int*   src = (const int*)d_in[1];
    const int*   dst = (const int*)d_in[2];
    const float* W1  = (const float*)d_in[3];
    const float* b1  = (const float*)d_in[4];
    const float* W2  = (const float*)d_in[5];
    const float* b2  = (const float*)d_in[6];
    float* out = (float*)d_out;

    const int N = in_sizes[0] / 128;
    const int E = in_sizes[1];

    // workspace layout (4-byte units):
    int*   bucket_cursor  = (int*)d_ws;            // 512 (the only memset)
    int*   bucket_cnt_part= bucket_cursor + 512;   // BDST*512 (atomic-free slices)
    int*   bucket_ptr     = bucket_cnt_part + BDST * NBUCK; // 513
    int*   row_ptr        = bucket_ptr + 513;      // N+1 (sentinel row_ptr[N]=E)
    float* norm_src       = (float*)(row_ptr + N + 1); // N
    float* norm_dst       = norm_src + N;          // N
    // t region: 256B-aligned (misalignment doubles gather FETCH).
    long long toff = (3LL * N + 512 + BDST * NBUCK + 514 + 63) & ~63LL;
    float* tbase    = (float*)d_ws + toff;         // N*32 floats (t_h = N*64 fp16; binned = E*8 B)
    float* h        = tbase + (long long)N * 32;   // N*64 fp32
    int*   csr      = (int*)(h + (long long)N * D); // E
    __half* t_h = (__half*)tbase;                  // interleaved [N x 64] fp16
    unsigned long long* binned = (unsigned long long*)tbase;  // dead before gemm1
    // hist staging aliases h (dead until k_agg layer 1):
    // NSH * ceil(ceil(N/2)/4) * 4B = 6.4 MB <= 25.6 MB region.
    unsigned* hstage = (unsigned*)h;

    const int NB = (N + 255) / 256;                // buckets used (391)
    const int NBK = (E + EPB - 1) / EPB;           // bin blocks (196)

    hipMemsetAsync(bucket_cursor, 0, 512 * sizeof(int), stream);

    k_histdst<<<BDST, 1024, 0, stream>>>(dst, bucket_cnt_part, E);
    k_scanB<<<1, 512, 0, stream>>>(bucket_cnt_part, bucket_ptr, row_ptr, N, E);
    k_binhist<<<NBK + NSH, 256, 0, stream>>>(src, dst, bucket_ptr, bucket_cursor,
                                             binned, hstage, E, N, NBK);
    k_bsort<<<NB, 256, 0, stream>>>(binned, bucket_ptr, hstage, csr, row_ptr,
                                    norm_src, norm_dst, N);

    // layer 1: t = (x W1) * norm_src ; h = relu(agg * norm_dst + b1)
    k_gemm_mfma<128><<<(N + 63) / 64, 256, 0, stream>>>(x, W1, norm_src, t_h, N);
    k_agg<<<(N + 7) / 8, 256, 0, stream>>>(row_ptr, csr, t_h, norm_dst, b1, h, N, 1);

    // layer 2: t = (h W2) * norm_src ; out = agg * norm_dst + b2
    k_gemm_mfma<64><<<(N + 63) / 64, 256, 0, stream>>>(h, W2, norm_src, t_h, N);
    k_agg<<<(N + 7) / 8, 256, 0, stream>>>(row_ptr, csr, t_h, norm_dst, b2, out, N, 0);
}

// Round 17
// 283.750 us; speedup vs baseline: 1.0017x; 1.0017x over previous
//
#include <hip/hip_runtime.h>
#include <hip/hip_fp16.h>

#define D 64          // hidden/output feature dim
#define NBUCK 512     // dst buckets (dst>>8), 391 used
#define EPB 4096      // edges per k_bin block (R5/R12-verified config)
#define SRC_BLOCKS 64 // one-pass src histogram blocks (packed byte counters)
#define BDST 16       // k_hist blocks dedicated to the dst bucket plane
#define HWORDS 25088  // LDS words >= ceil(N/4) for N<=100352
#define BSTAGE 8192   // k_bsort LDS stage capacity (edges); avg bucket ~4090

typedef __attribute__((ext_vector_type(8))) short short8;   // 8 bf16 (4 VGPRs)
typedef __attribute__((ext_vector_type(4))) float floatx4;  // 4 fp32 acc

// ---------------------------------------------------------------------------
// One-pass histogram, NO global atomics anywhere (R8 lesson: device-scope
// global atomics bypass L2 -> ~40x too slow). R12-verified.
// ---------------------------------------------------------------------------
__global__ __launch_bounds__(1024) void k_hist(const int* __restrict__ src,
                                               const int* __restrict__ dst,
                                               unsigned* __restrict__ hstage,
                                               int* __restrict__ bucket_cnt_part,
                                               int E, int N) {
    const int E4 = E >> 2;
    int tid = threadIdx.x;

    if (blockIdx.x < BDST) {
        // ---- dst bucket count plane (private slice, atomic-free output) ----
        __shared__ int hb[NBUCK];
        for (int i = tid; i < NBUCK; i += 1024) hb[i] = 0;
        __syncthreads();
        const int4* d4 = (const int4*)dst;
        int stride = BDST * 1024;
        for (int i = blockIdx.x * 1024 + tid; i < E4; i += stride) {
            int4 v = d4[i];
            atomicAdd(&hb[v.x >> 8], 1);
            atomicAdd(&hb[v.y >> 8], 1);
            atomicAdd(&hb[v.z >> 8], 1);
            atomicAdd(&hb[v.w >> 8], 1);
        }
        if (blockIdx.x == 0) {
            int e = E4 * 4 + tid;
            if (e < E) atomicAdd(&hb[dst[e] >> 8], 1);
        }
        __syncthreads();
        int* my = bucket_cnt_part + blockIdx.x * NBUCK;
        for (int i = tid; i < NBUCK; i += 1024) my[i] = hb[i];
    } else {
        // ---- src out-degree plane: packed byte-lane LDS counters ----
        __shared__ unsigned hw[HWORDS];
        int wlen = (N + 3) >> 2;
        for (int i = tid; i < wlen; i += 1024) hw[i] = 0;
        __syncthreads();
        const int4* s4 = (const int4*)src;
        int b = blockIdx.x - BDST;
        int stride = SRC_BLOCKS * 1024;
        for (int i = b * 1024 + tid; i < E4; i += stride) {
            int4 v = s4[i];
            atomicAdd(&hw[v.x >> 2], 1u << ((v.x & 3) * 8));
            atomicAdd(&hw[v.y >> 2], 1u << ((v.y & 3) * 8));
            atomicAdd(&hw[v.z >> 2], 1u << ((v.z & 3) * 8));
            atomicAdd(&hw[v.w >> 2], 1u << ((v.w & 3) * 8));
        }
        if (b == 0) {
            int e = E4 * 4 + tid;
            if (e < E) {
                int v = src[e];
                atomicAdd(&hw[v >> 2], 1u << ((v & 3) * 8));
            }
        }
        __syncthreads();
        unsigned* my = hstage + (long long)b * wlen;
        for (int i = tid; i < wlen; i += 1024) my[i] = hw[i];   // coalesced
    }
}

// ---- fold BDST bucket-count slices + exclusive scan + sentinels ----
__global__ __launch_bounds__(512) void k_scanB(const int* __restrict__ bucket_cnt_part,
                                               int* __restrict__ bucket_ptr,
                                               int* __restrict__ row_ptr, int N, int E) {
    __shared__ int s[512];
    int tid = threadIdx.x;
    int v = 0;
#pragma unroll
    for (int b = 0; b < BDST; ++b) v += bucket_cnt_part[b * NBUCK + tid];
    s[tid] = v;
    __syncthreads();
    for (int off = 1; off < 512; off <<= 1) {
        int add = (tid >= off) ? s[tid - off] : 0;
        __syncthreads();
        s[tid] += add;
        __syncthreads();
    }
    bucket_ptr[tid] = s[tid] - v;          // exclusive
    if (tid == 511) bucket_ptr[512] = s[511];
    if (tid == 0) row_ptr[N] = E;          // sentinel for k_agg's rp[i+1]
}

// ---------------------------------------------------------------------------
// Binned CSR build (R12-verified config: EPB 4096, 256 threads).
// ---------------------------------------------------------------------------
__global__ __launch_bounds__(256) void k_bin(const int* __restrict__ src,
                                             const int* __restrict__ dst,
                                             const int* __restrict__ bucket_ptr,
                                             int* __restrict__ bucket_cursor,
                                             unsigned long long* __restrict__ binned,
                                             int E) {
    __shared__ int cnt[NBUCK];
    __shared__ int bloc[NBUCK];
    __shared__ int lcur[NBUCK];
    __shared__ int gbase[NBUCK];
    __shared__ int ss[256];
    __shared__ unsigned long long stage[EPB];

    int tid = threadIdx.x;
    int start = blockIdx.x * EPB;
    int nloc = min(EPB, E - start);

    for (int i = tid; i < NBUCK; i += 256) cnt[i] = 0;
    __syncthreads();

#pragma unroll
    for (int r = 0; r < EPB / 256; ++r) {
        int idx = start + r * 256 + tid;
        if (idx < E) atomicAdd(&cnt[dst[idx] >> 8], 1);
    }
    __syncthreads();

    int a = cnt[2 * tid], b = cnt[2 * tid + 1];
    ss[tid] = a + b;
    __syncthreads();
    for (int off = 1; off < 256; off <<= 1) {
        int add = (tid >= off) ? ss[tid - off] : 0;
        __syncthreads();
        ss[tid] += add;
        __syncthreads();
    }
    int excl = ss[tid] - (a + b);
    bloc[2 * tid] = excl;           lcur[2 * tid] = excl;
    bloc[2 * tid + 1] = excl + a;   lcur[2 * tid + 1] = excl + a;
    __syncthreads();

    for (int bk = tid; bk < NBUCK; bk += 256) {
        int c = cnt[bk];
        gbase[bk] = c ? (atomicAdd(&bucket_cursor[bk], c) + bucket_ptr[bk]) : 0;
    }
    __syncthreads();

#pragma unroll
    for (int r = 0; r < EPB / 256; ++r) {
        int idx = start + r * 256 + tid;
        if (idx < E) {
            int d = dst[idx];
            int p = atomicAdd(&lcur[d >> 8], 1);
            stage[p] = ((unsigned long long)(unsigned)d << 32) | (unsigned)src[idx];
        }
    }
    __syncthreads();

#pragma unroll
    for (int r = 0; r < EPB / 256; ++r) {
        int i = r * 256 + tid;
        if (i < nloc) {
            unsigned long long e = stage[i];
            int bk = (int)(e >> 40);
            binned[gbase[bk] + (i - bloc[bk])] = e;
        }
    }
}

// ---------------------------------------------------------------------------
// Per-bucket sort. R16: fully LDS-sorted — stage bucket in est[] (64KB),
// scatter src ids to LOCAL positions in csr_lds[] (32KB) via LDS atomics,
// then write csr out COALESCED. Kills the 1.7M-line 4B global scatter
// (~8 cy/line-touch/CU empirical law -> ~21 us hidden cost).
// Fallback to the global-scatter path if a bucket exceeds BSTAGE.
// Also derives row_ptr + both norms (folding SRC_BLOCKS byte-lane hists).
// ---------------------------------------------------------------------------
__global__ __launch_bounds__(256) void k_bsort(const unsigned long long* __restrict__ binned,
                                               const int* __restrict__ bucket_ptr,
                                               const unsigned* __restrict__ hstage,
                                               int* __restrict__ csr,
                                               int* __restrict__ row_ptr,
                                               float* __restrict__ norm_src,
                                               float* __restrict__ norm_dst, int N) {
    __shared__ unsigned long long est[BSTAGE];   // 64 KB
    __shared__ int csr_lds[BSTAGE];              // 32 KB
    __shared__ int cnt256[256];
    __shared__ int ss[256];
    __shared__ int cur[256];
    int b = blockIdx.x;
    int n0 = b << 8;
    int tid = threadIdx.x;
    int base = bucket_ptr[b];
    int ctot = bucket_ptr[b + 1] - base;
    bool fits = (ctot <= BSTAGE);

    cnt256[tid] = 0;
    __syncthreads();

    if (fits) {
        for (int k = tid; k < ctot; k += 256) {
            unsigned long long e = binned[base + k];   // single global read
            est[k] = e;
            atomicAdd(&cnt256[(int)(e >> 32) - n0], 1);
        }
    } else {
        for (int k = tid; k < ctot; k += 256)
            atomicAdd(&cnt256[(int)(binned[base + k] >> 32) - n0], 1);
    }
    __syncthreads();

    int v = cnt256[tid];
    ss[tid] = v;
    __syncthreads();
    for (int off = 1; off < 256; off <<= 1) {
        int add = (tid >= off) ? ss[tid - off] : 0;
        __syncthreads();
        ss[tid] += add;
        __syncthreads();
    }
    int excl = ss[tid] - v;
    int node = n0 + tid;
    if (node < N) {
        row_ptr[node] = base + excl;
        norm_dst[node] = rsqrtf((float)v + 1.0f);            // +1 self loop
        int wlen = (N + 3) >> 2;
        unsigned sh = (unsigned)(node & 3) * 8u;
        const unsigned* q = hstage + (node >> 2);
        int od = 0;
#pragma unroll 8
        for (int p = 0; p < SRC_BLOCKS; ++p) {
            od += (int)((*q >> sh) & 0xffu);
            q += wlen;
        }
        norm_src[node] = rsqrtf((float)od + 1.0f);
    }
    cur[tid] = fits ? excl : (base + excl);      // local offsets when LDS-sorted
    __syncthreads();

    if (fits) {
        for (int k = tid; k < ctot; k += 256) {
            unsigned long long e = est[k];
            int p = atomicAdd(&cur[(int)(e >> 32) - n0], 1);
            csr_lds[p] = (int)(e & 0xffffffffu);  // LDS scatter
        }
        __syncthreads();
        for (int k = tid; k < ctot; k += 256)
            csr[base + k] = csr_lds[k];           // coalesced global write
    } else {
        for (int k = tid; k < ctot; k += 256) {
            unsigned long long e = binned[base + k];
            int p = atomicAdd(&cur[(int)(e >> 32) - n0], 1);
            csr[p] = (int)(e & 0xffffffffu);
        }
    }
}

// ---------------------------------------------------------------------------
// MFMA dense layer via split-bf16 (verbatim, interleaved t layout)
// ---------------------------------------------------------------------------
template <int K>
__global__ __launch_bounds__(256) void k_gemm_mfma(const float* __restrict__ hsrc,
                                                   const float* __restrict__ W,   // [K,64] row-major
                                                   const float* __restrict__ norm_src,
                                                   __half* __restrict__ t, int N) {
    constexpr int NKI = K / 32;
    __shared__ short Whi[NKI * 2048];
    __shared__ short Wlo[NKI * 2048];
    int tid = threadIdx.x;

    for (int f = tid; f < K * 64; f += 256) {
        int n  = f & 15;
        int j  = (f >> 4) & 7;
        int q  = (f >> 7) & 3;
        int ct = (f >> 9) & 3;
        int ki = f >> 11;
        int k = ki * 32 + q * 8 + j;
        int c = ct * 16 + n;
        float w = W[k * 64 + c];
        unsigned u = __float_as_uint(w);
        float l = w - __uint_as_float(u & 0xffff0000u);
        int idx = (((ki * 4 + ct) * 16 + n) * 4 + q) * 8 + j;
        Whi[idx] = (short)(u >> 16);
        Wlo[idx] = (short)(__float_as_uint(l) >> 16);
    }
    __syncthreads();

    int wave = tid >> 6, lane = tid & 63;
    int q = lane >> 4, n = lane & 15;
    int r0 = blockIdx.x * 64 + wave * 16;
    int rowc = min(r0 + n, N - 1);

    floatx4 acc[4] = {{0.f,0.f,0.f,0.f},{0.f,0.f,0.f,0.f},
                      {0.f,0.f,0.f,0.f},{0.f,0.f,0.f,0.f}};

    for (int ki = 0; ki < NKI; ++ki) {
        const float* ap = hsrc + (long long)rowc * K + ki * 32 + q * 8;
        float4 a0 = *(const float4*)ap;
        float4 a1 = *(const float4*)(ap + 4);
        float av[8] = {a0.x, a0.y, a0.z, a0.w, a1.x, a1.y, a1.z, a1.w};
        short8 ahi, alo;
#pragma unroll
        for (int j = 0; j < 8; ++j) {
            unsigned u = __float_as_uint(av[j]);
            float l = av[j] - __uint_as_float(u & 0xffff0000u);
            ahi[j] = (short)(u >> 16);
            alo[j] = (short)(__float_as_uint(l) >> 16);
        }
#pragma unroll
        for (int ct = 0; ct < 4; ++ct) {
            int bidx = (((ki * 4 + ct) * 16 + n) * 4 + q) * 8;
            short8 bhi = *(const short8*)&Whi[bidx];
            short8 blo = *(const short8*)&Wlo[bidx];
            acc[ct] = __builtin_amdgcn_mfma_f32_16x16x32_bf16(ahi, bhi, acc[ct], 0, 0, 0);
            acc[ct] = __builtin_amdgcn_mfma_f32_16x16x32_bf16(ahi, blo, acc[ct], 0, 0, 0);
            acc[ct] = __builtin_amdgcn_mfma_f32_16x16x32_bf16(alo, bhi, acc[ct], 0, 0, 0);
        }
    }

#pragma unroll
    for (int reg = 0; reg < 4; ++reg) {
        int orow = r0 + q * 4 + reg;
        if (orow < N) {
            float nrm = norm_src[orow];
#pragma unroll
            for (int ct = 0; ct < 4; ++ct)
                t[(long long)orow * 64 + ct * 16 + n] = __float2half(acc[ct][reg] * nrm);
        }
    }
}

// ---------------------------------------------------------------------------
// gather-aggregate (R9-verified 8-deep form; at the ~8 cy/line-touch wall:
// (E+N) x 2 lines -> ~45.5 us. 16-deep (R12) and FETCH-reduction (R1) null).
// ---------------------------------------------------------------------------
__global__ __launch_bounds__(256) void k_agg(const int* __restrict__ row_ptr,
                                             const int* __restrict__ csr,
                                             const __half* __restrict__ t,
                                             const float* __restrict__ norm_dst,
                                             const float* __restrict__ bias,
                                             float* __restrict__ out, int N, int do_relu) {
    int tid = threadIdx.x;
    int half_id = tid >> 5;
    int lane = tid & 31;
    int i = blockIdx.x * 8 + half_id;
    if (i >= N) return;
    const __half2* t2 = (const __half2*)t;
    int start = row_ptr[i];
    int c = row_ptr[i + 1] - start;

    float2 sf = __half22float2(t2[i * 32 + lane]);
    float ax = sf.x, ay = sf.y;

    int j = 0;
    int pre = min(c, (4 - (start & 3)) & 3);   // align csr pointer to 16B
    for (; j < pre; ++j) {
        float2 f = __half22float2(t2[csr[start + j] * 32 + lane]);
        ax += f.x; ay += f.y;
    }
    for (; j + 8 <= c; j += 8) {
        int4 s4 = *(const int4*)&csr[start + j];
        int4 s5 = *(const int4*)&csr[start + j + 4];
        float2 f0 = __half22float2(t2[s4.x * 32 + lane]);
        float2 f1 = __half22float2(t2[s4.y * 32 + lane]);
        float2 f2 = __half22float2(t2[s4.z * 32 + lane]);
        float2 f3 = __half22float2(t2[s4.w * 32 + lane]);
        float2 f4 = __half22float2(t2[s5.x * 32 + lane]);
        float2 f5 = __half22float2(t2[s5.y * 32 + lane]);
        float2 f6 = __half22float2(t2[s5.z * 32 + lane]);
        float2 f7 = __half22float2(t2[s5.w * 32 + lane]);
        ax += ((f0.x + f1.x) + (f2.x + f3.x)) + ((f4.x + f5.x) + (f6.x + f7.x));
        ay += ((f0.y + f1.y) + (f2.y + f3.y)) + ((f4.y + f5.y) + (f6.y + f7.y));
    }
    for (; j + 4 <= c; j += 4) {
        int4 s4 = *(const int4*)&csr[start + j];
        float2 f0 = __half22float2(t2[s4.x * 32 + lane]);
        float2 f1 = __half22float2(t2[s4.y * 32 + lane]);
        float2 f2 = __half22float2(t2[s4.z * 32 + lane]);
        float2 f3 = __half22float2(t2[s4.w * 32 + lane]);
        ax += (f0.x + f1.x) + (f2.x + f3.x);
        ay += (f0.y + f1.y) + (f2.y + f3.y);
    }
    for (; j < c; ++j) {
        float2 f = __half22float2(t2[csr[start + j] * 32 + lane]);
        ax += f.x; ay += f.y;
    }

    float nrm = norm_dst[i];
    float2 bb = ((const float2*)bias)[lane];
    float vx = fmaf(ax, nrm, bb.x);
    float vy = fmaf(ay, nrm, bb.y);
    if (do_relu) { vx = fmaxf(vx, 0.f); vy = fmaxf(vy, 0.f); }
    float2 o; o.x = vx; o.y = vy;
    ((float2*)out)[i * 32 + lane] = o;
}

extern "C" void kernel_launch(void* const* d_in, const int* in_sizes, int n_in,
                              void* d_out, int out_size, void* d_ws, size_t ws_size,
                              hipStream_t stream) {
    const float* x   = (const float*)d_in[0];
    const int*   src = (const int*)d_in[1];
    const int*   dst = (const int*)d_in[2];
    const float* W1  = (const float*)d_in[3];
    const float* b1  = (const float*)d_in[4];
    const float* W2  = (const float*)d_in[5];
    const float* b2  = (const float*)d_in[6];
    float* out = (float*)d_out;

    const int N = in_sizes[0] / 128;
    const int E = in_sizes[1];

    // workspace layout (4-byte units):
    int*   bucket_cursor  = (int*)d_ws;            // 512 (the only memset)
    int*   bucket_cnt_part= bucket_cursor + 512;   // BDST*512 (atomic-free slices)
    int*   bucket_ptr     = bucket_cnt_part + BDST * NBUCK; // 513
    int*   row_ptr        = bucket_ptr + 513;      // N+1 (sentinel row_ptr[N]=E)
    float* norm_src       = (float*)(row_ptr + N + 1); // N
    float* norm_dst       = norm_src + N;          // N
    // t region: 256B-aligned (misalignment doubles gather FETCH).
    long long toff = (3LL * N + 512 + BDST * NBUCK + 514 + 63) & ~63LL;
    float* tbase    = (float*)d_ws + toff;         // N*32 floats (t_h = N*64 fp16; binned = E*8 B)
    float* h        = tbase + (long long)N * 32;   // N*64 fp32
    int*   csr      = (int*)(h + (long long)N * D); // E
    __half* t_h = (__half*)tbase;                  // interleaved [N x 64] fp16
    unsigned long long* binned = (unsigned long long*)tbase;  // dead before gemm1
    // hist staging aliases h (dead until k_agg layer 1): 64*ceil(N/4)*4B = 6.4 MB
    unsigned* hstage = (unsigned*)h;

    const int NB = (N + 255) / 256;                // buckets used (391)
    const int NBK = (E + EPB - 1) / EPB;

    hipMemsetAsync(bucket_cursor, 0, 512 * sizeof(int), stream);

    k_hist<<<BDST + SRC_BLOCKS, 1024, 0, stream>>>(src, dst, hstage, bucket_cnt_part, E, N);
    k_scanB<<<1, 512, 0, stream>>>(bucket_cnt_part, bucket_ptr, row_ptr, N, E);
    k_bin<<<NBK, 256, 0, stream>>>(src, dst, bucket_ptr, bucket_cursor, binned, E);
    k_bsort<<<NB, 256, 0, stream>>>(binned, bucket_ptr, hstage, csr, row_ptr,
                                    norm_src, norm_dst, N);

    // layer 1: t = (x W1) * norm_src ; h = relu(agg * norm_dst + b1)
    k_gemm_mfma<128><<<(N + 63) / 64, 256, 0, stream>>>(x, W1, norm_src, t_h, N);
    k_agg<<<(N + 7) / 8, 256, 0, stream>>>(row_ptr, csr, t_h, norm_dst, b1, h, N, 1);

    // layer 2: t = (h W2) * norm_src ; out = agg * norm_dst + b2
    k_gemm_mfma<64><<<(N + 63) / 64, 256, 0, stream>>>(h, W2, norm_src, t_h, N);
    k_agg<<<(N + 7) / 8, 256, 0, stream>>>(row_ptr, csr, t_h, norm_dst, b2, out, N, 0);
}

// Round 18
// 274.803 us; speedup vs baseline: 1.0343x; 1.0326x over previous
//
#include <hip/hip_runtime.h>
#include <hip/hip_fp16.h>

#define D 64          // hidden/output feature dim
#define NBUCK 512     // dst buckets (dst>>8), 391 used
#define EPB 4096      // edges per k_bin block (R5/R12-verified config)
#define SRC_BLOCKS 64 // one-pass src histogram blocks (packed byte counters)
#define BDST 16       // k_hist blocks dedicated to the dst bucket plane
#define HWORDS 25088  // LDS words >= ceil(N/4) for N<=100352
#define BSTAGE 8192   // k_bsort LDS stage capacity (edges); avg bucket ~4090

typedef __attribute__((ext_vector_type(8))) short short8;   // 8 bf16 (4 VGPRs)
typedef __attribute__((ext_vector_type(4))) float floatx4;  // 4 fp32 acc

// ---------------------------------------------------------------------------
// One-pass histogram, NO global atomics anywhere (R8 lesson: device-scope
// global atomics bypass L2 -> ~40x too slow). R12-verified, except the
// src-plane dump now writes TILED-TRANSPOSED layout:
//   hstage[tile*1024 + b*16 + j]  for word i = tile*16+j
// Each 16-thread group writes one 64B chunk (coalesced); the bsort fold
// becomes tile-local (16x fewer L2 line-touches).
// ---------------------------------------------------------------------------
__global__ __launch_bounds__(1024) void k_hist(const int* __restrict__ src,
                                               const int* __restrict__ dst,
                                               unsigned* __restrict__ hstage,
                                               int* __restrict__ bucket_cnt_part,
                                               int E, int N) {
    const int E4 = E >> 2;
    int tid = threadIdx.x;

    if (blockIdx.x < BDST) {
        // ---- dst bucket count plane (private slice, atomic-free output) ----
        __shared__ int hb[NBUCK];
        for (int i = tid; i < NBUCK; i += 1024) hb[i] = 0;
        __syncthreads();
        const int4* d4 = (const int4*)dst;
        int stride = BDST * 1024;
        for (int i = blockIdx.x * 1024 + tid; i < E4; i += stride) {
            int4 v = d4[i];
            atomicAdd(&hb[v.x >> 8], 1);
            atomicAdd(&hb[v.y >> 8], 1);
            atomicAdd(&hb[v.z >> 8], 1);
            atomicAdd(&hb[v.w >> 8], 1);
        }
        if (blockIdx.x == 0) {
            int e = E4 * 4 + tid;
            if (e < E) atomicAdd(&hb[dst[e] >> 8], 1);
        }
        __syncthreads();
        int* my = bucket_cnt_part + blockIdx.x * NBUCK;
        for (int i = tid; i < NBUCK; i += 1024) my[i] = hb[i];
    } else {
        // ---- src out-degree plane: packed byte-lane LDS counters ----
        __shared__ unsigned hw[HWORDS];
        int wlen = (N + 3) >> 2;
        for (int i = tid; i < wlen; i += 1024) hw[i] = 0;
        __syncthreads();
        const int4* s4 = (const int4*)src;
        int b = blockIdx.x - BDST;
        int stride = SRC_BLOCKS * 1024;
        for (int i = b * 1024 + tid; i < E4; i += stride) {
            int4 v = s4[i];
            atomicAdd(&hw[v.x >> 2], 1u << ((v.x & 3) * 8));
            atomicAdd(&hw[v.y >> 2], 1u << ((v.y & 3) * 8));
            atomicAdd(&hw[v.z >> 2], 1u << ((v.z & 3) * 8));
            atomicAdd(&hw[v.w >> 2], 1u << ((v.w & 3) * 8));
        }
        if (b == 0) {
            int e = E4 * 4 + tid;
            if (e < E) {
                int v = src[e];
                atomicAdd(&hw[v >> 2], 1u << ((v & 3) * 8));
            }
        }
        __syncthreads();
        // tiled-transposed dump: word i -> hstage[(i>>4)*1024 + b*16 + (i&15)]
        for (int i = tid; i < wlen; i += 1024)
            hstage[((long long)(i >> 4) << 10) + (b << 4) + (i & 15)] = hw[i];
    }
}

// ---- fold BDST bucket-count slices + exclusive scan + sentinels ----
__global__ __launch_bounds__(512) void k_scanB(const int* __restrict__ bucket_cnt_part,
                                               int* __restrict__ bucket_ptr,
                                               int* __restrict__ row_ptr, int N, int E) {
    __shared__ int s[512];
    int tid = threadIdx.x;
    int v = 0;
#pragma unroll
    for (int b = 0; b < BDST; ++b) v += bucket_cnt_part[b * NBUCK + tid];
    s[tid] = v;
    __syncthreads();
    for (int off = 1; off < 512; off <<= 1) {
        int add = (tid >= off) ? s[tid - off] : 0;
        __syncthreads();
        s[tid] += add;
        __syncthreads();
    }
    bucket_ptr[tid] = s[tid] - v;          // exclusive
    if (tid == 511) bucket_ptr[512] = s[511];
    if (tid == 0) row_ptr[N] = E;          // sentinel for k_agg's rp[i+1]
}

// ---------------------------------------------------------------------------
// Binned CSR build (R12-verified config: EPB 4096, 256 threads).
// ---------------------------------------------------------------------------
__global__ __launch_bounds__(256) void k_bin(const int* __restrict__ src,
                                             const int* __restrict__ dst,
                                             const int* __restrict__ bucket_ptr,
                                             int* __restrict__ bucket_cursor,
                                             unsigned long long* __restrict__ binned,
                                             int E) {
    __shared__ int cnt[NBUCK];
    __shared__ int bloc[NBUCK];
    __shared__ int lcur[NBUCK];
    __shared__ int gbase[NBUCK];
    __shared__ int ss[256];
    __shared__ unsigned long long stage[EPB];

    int tid = threadIdx.x;
    int start = blockIdx.x * EPB;
    int nloc = min(EPB, E - start);

    for (int i = tid; i < NBUCK; i += 256) cnt[i] = 0;
    __syncthreads();

#pragma unroll
    for (int r = 0; r < EPB / 256; ++r) {
        int idx = start + r * 256 + tid;
        if (idx < E) atomicAdd(&cnt[dst[idx] >> 8], 1);
    }
    __syncthreads();

    int a = cnt[2 * tid], b = cnt[2 * tid + 1];
    ss[tid] = a + b;
    __syncthreads();
    for (int off = 1; off < 256; off <<= 1) {
        int add = (tid >= off) ? ss[tid - off] : 0;
        __syncthreads();
        ss[tid] += add;
        __syncthreads();
    }
    int excl = ss[tid] - (a + b);
    bloc[2 * tid] = excl;           lcur[2 * tid] = excl;
    bloc[2 * tid + 1] = excl + a;   lcur[2 * tid + 1] = excl + a;
    __syncthreads();

    for (int bk = tid; bk < NBUCK; bk += 256) {
        int c = cnt[bk];
        gbase[bk] = c ? (atomicAdd(&bucket_cursor[bk], c) + bucket_ptr[bk]) : 0;
    }
    __syncthreads();

#pragma unroll
    for (int r = 0; r < EPB / 256; ++r) {
        int idx = start + r * 256 + tid;
        if (idx < E) {
            int d = dst[idx];
            int p = atomicAdd(&lcur[d >> 8], 1);
            stage[p] = ((unsigned long long)(unsigned)d << 32) | (unsigned)src[idx];
        }
    }
    __syncthreads();

#pragma unroll
    for (int r = 0; r < EPB / 256; ++r) {
        int i = r * 256 + tid;
        if (i < nloc) {
            unsigned long long e = stage[i];
            int bk = (int)(e >> 40);
            binned[gbase[bk] + (i - bloc[bk])] = e;
        }
    }
}

// ---------------------------------------------------------------------------
// Per-bucket sort (R12-verified form: one-pass est staging, global csr
// scatter — R17 proved LDS-scatter regresses). Fold now reads the TILED
// hstage layout: per p-slice a wave touches exactly ONE 64B line
// (16 consecutive words) -> 64 lines/wave vs 1024 in the strided layout.
// ---------------------------------------------------------------------------
__global__ __launch_bounds__(256) void k_bsort(const unsigned long long* __restrict__ binned,
                                               const int* __restrict__ bucket_ptr,
                                               const unsigned* __restrict__ hstage,
                                               int* __restrict__ csr,
                                               int* __restrict__ row_ptr,
                                               float* __restrict__ norm_src,
                                               float* __restrict__ norm_dst, int N) {
    __shared__ unsigned long long est[BSTAGE];
    __shared__ int cnt256[256];
    __shared__ int ss[256];
    __shared__ int cur[256];
    int b = blockIdx.x;
    int n0 = b << 8;
    int tid = threadIdx.x;
    int base = bucket_ptr[b];
    int ctot = bucket_ptr[b + 1] - base;
    bool fits = (ctot <= BSTAGE);

    cnt256[tid] = 0;
    __syncthreads();

    if (fits) {
        for (int k = tid; k < ctot; k += 256) {
            unsigned long long e = binned[base + k];   // single global read
            est[k] = e;
            atomicAdd(&cnt256[(int)(e >> 32) - n0], 1);
        }
    } else {
        for (int k = tid; k < ctot; k += 256)
            atomicAdd(&cnt256[(int)(binned[base + k] >> 32) - n0], 1);
    }
    __syncthreads();

    int v = cnt256[tid];
    ss[tid] = v;
    __syncthreads();
    for (int off = 1; off < 256; off <<= 1) {
        int add = (tid >= off) ? ss[tid - off] : 0;
        __syncthreads();
        ss[tid] += add;
        __syncthreads();
    }
    int excl = ss[tid] - v;
    int node = n0 + tid;
    if (node < N) {
        row_ptr[node] = base + excl;
        norm_dst[node] = rsqrtf((float)v + 1.0f);            // +1 self loop
        // tiled fold: word w=node>>2 lives at hstage[(w>>4)*1024 + p*16 + (w&15)]
        int w = node >> 2;
        unsigned sh = (unsigned)(node & 3) * 8u;
        const unsigned* q = hstage + ((long long)(w >> 4) << 10) + (w & 15);
        int od = 0;
#pragma unroll 8
        for (int p = 0; p < SRC_BLOCKS; ++p) {
            od += (int)((*q >> sh) & 0xffu);
            q += 16;
        }
        norm_src[node] = rsqrtf((float)od + 1.0f);
    }
    cur[tid] = base + excl;
    __syncthreads();

    if (fits) {
        for (int k = tid; k < ctot; k += 256) {
            unsigned long long e = est[k];
            int p = atomicAdd(&cur[(int)(e >> 32) - n0], 1);
            csr[p] = (int)(e & 0xffffffffu);
        }
    } else {
        for (int k = tid; k < ctot; k += 256) {
            unsigned long long e = binned[base + k];
            int p = atomicAdd(&cur[(int)(e >> 32) - n0], 1);
            csr[p] = (int)(e & 0xffffffffu);
        }
    }
}

// ---------------------------------------------------------------------------
// MFMA dense layer via split-bf16 (verbatim, interleaved t layout)
// ---------------------------------------------------------------------------
template <int K>
__global__ __launch_bounds__(256) void k_gemm_mfma(const float* __restrict__ hsrc,
                                                   const float* __restrict__ W,   // [K,64] row-major
                                                   const float* __restrict__ norm_src,
                                                   __half* __restrict__ t, int N) {
    constexpr int NKI = K / 32;
    __shared__ short Whi[NKI * 2048];
    __shared__ short Wlo[NKI * 2048];
    int tid = threadIdx.x;

    for (int f = tid; f < K * 64; f += 256) {
        int n  = f & 15;
        int j  = (f >> 4) & 7;
        int q  = (f >> 7) & 3;
        int ct = (f >> 9) & 3;
        int ki = f >> 11;
        int k = ki * 32 + q * 8 + j;
        int c = ct * 16 + n;
        float w = W[k * 64 + c];
        unsigned u = __float_as_uint(w);
        float l = w - __uint_as_float(u & 0xffff0000u);
        int idx = (((ki * 4 + ct) * 16 + n) * 4 + q) * 8 + j;
        Whi[idx] = (short)(u >> 16);
        Wlo[idx] = (short)(__float_as_uint(l) >> 16);
    }
    __syncthreads();

    int wave = tid >> 6, lane = tid & 63;
    int q = lane >> 4, n = lane & 15;
    int r0 = blockIdx.x * 64 + wave * 16;
    int rowc = min(r0 + n, N - 1);

    floatx4 acc[4] = {{0.f,0.f,0.f,0.f},{0.f,0.f,0.f,0.f},
                      {0.f,0.f,0.f,0.f},{0.f,0.f,0.f,0.f}};

    for (int ki = 0; ki < NKI; ++ki) {
        const float* ap = hsrc + (long long)rowc * K + ki * 32 + q * 8;
        float4 a0 = *(const float4*)ap;
        float4 a1 = *(const float4*)(ap + 4);
        float av[8] = {a0.x, a0.y, a0.z, a0.w, a1.x, a1.y, a1.z, a1.w};
        short8 ahi, alo;
#pragma unroll
        for (int j = 0; j < 8; ++j) {
            unsigned u = __float_as_uint(av[j]);
            float l = av[j] - __uint_as_float(u & 0xffff0000u);
            ahi[j] = (short)(u >> 16);
            alo[j] = (short)(__float_as_uint(l) >> 16);
        }
#pragma unroll
        for (int ct = 0; ct < 4; ++ct) {
            int bidx = (((ki * 4 + ct) * 16 + n) * 4 + q) * 8;
            short8 bhi = *(const short8*)&Whi[bidx];
            short8 blo = *(const short8*)&Wlo[bidx];
            acc[ct] = __builtin_amdgcn_mfma_f32_16x16x32_bf16(ahi, bhi, acc[ct], 0, 0, 0);
            acc[ct] = __builtin_amdgcn_mfma_f32_16x16x32_bf16(ahi, blo, acc[ct], 0, 0, 0);
            acc[ct] = __builtin_amdgcn_mfma_f32_16x16x32_bf16(alo, bhi, acc[ct], 0, 0, 0);
        }
    }

#pragma unroll
    for (int reg = 0; reg < 4; ++reg) {
        int orow = r0 + q * 4 + reg;
        if (orow < N) {
            float nrm = norm_src[orow];
#pragma unroll
            for (int ct = 0; ct < 4; ++ct)
                t[(long long)orow * 64 + ct * 16 + n] = __float2half(acc[ct][reg] * nrm);
        }
    }
}

// ---------------------------------------------------------------------------
// gather-aggregate (R9-verified 8-deep form; at the line-touch wall:
// (E+N) x 2 lines -> ~45.5 us. 16-deep (R12) and FETCH-reduction (R1) null).
// ---------------------------------------------------------------------------
__global__ __launch_bounds__(256) void k_agg(const int* __restrict__ row_ptr,
                                             const int* __restrict__ csr,
                                             const __half* __restrict__ t,
                                             const float* __restrict__ norm_dst,
                                             const float* __restrict__ bias,
                                             float* __restrict__ out, int N, int do_relu) {
    int tid = threadIdx.x;
    int half_id = tid >> 5;
    int lane = tid & 31;
    int i = blockIdx.x * 8 + half_id;
    if (i >= N) return;
    const __half2* t2 = (const __half2*)t;
    int start = row_ptr[i];
    int c = row_ptr[i + 1] - start;

    float2 sf = __half22float2(t2[i * 32 + lane]);
    float ax = sf.x, ay = sf.y;

    int j = 0;
    int pre = min(c, (4 - (start & 3)) & 3);   // align csr pointer to 16B
    for (; j < pre; ++j) {
        float2 f = __half22float2(t2[csr[start + j] * 32 + lane]);
        ax += f.x; ay += f.y;
    }
    for (; j + 8 <= c; j += 8) {
        int4 s4 = *(const int4*)&csr[start + j];
        int4 s5 = *(const int4*)&csr[start + j + 4];
        float2 f0 = __half22float2(t2[s4.x * 32 + lane]);
        float2 f1 = __half22float2(t2[s4.y * 32 + lane]);
        float2 f2 = __half22float2(t2[s4.z * 32 + lane]);
        float2 f3 = __half22float2(t2[s4.w * 32 + lane]);
        float2 f4 = __half22float2(t2[s5.x * 32 + lane]);
        float2 f5 = __half22float2(t2[s5.y * 32 + lane]);
        float2 f6 = __half22float2(t2[s5.z * 32 + lane]);
        float2 f7 = __half22float2(t2[s5.w * 32 + lane]);
        ax += ((f0.x + f1.x) + (f2.x + f3.x)) + ((f4.x + f5.x) + (f6.x + f7.x));
        ay += ((f0.y + f1.y) + (f2.y + f3.y)) + ((f4.y + f5.y) + (f6.y + f7.y));
    }
    for (; j + 4 <= c; j += 4) {
        int4 s4 = *(const int4*)&csr[start + j];
        float2 f0 = __half22float2(t2[s4.x * 32 + lane]);
        float2 f1 = __half22float2(t2[s4.y * 32 + lane]);
        float2 f2 = __half22float2(t2[s4.z * 32 + lane]);
        float2 f3 = __half22float2(t2[s4.w * 32 + lane]);
        ax += (f0.x + f1.x) + (f2.x + f3.x);
        ay += (f0.y + f1.y) + (f2.y + f3.y);
    }
    for (; j < c; ++j) {
        float2 f = __half22float2(t2[csr[start + j] * 32 + lane]);
        ax += f.x; ay += f.y;
    }

    float nrm = norm_dst[i];
    float2 bb = ((const float2*)bias)[lane];
    float vx = fmaf(ax, nrm, bb.x);
    float vy = fmaf(ay, nrm, bb.y);
    if (do_relu) { vx = fmaxf(vx, 0.f); vy = fmaxf(vy, 0.f); }
    float2 o; o.x = vx; o.y = vy;
    ((float2*)out)[i * 32 + lane] = o;
}

extern "C" void kernel_launch(void* const* d_in, const int* in_sizes, int n_in,
                              void* d_out, int out_size, void* d_ws, size_t ws_size,
                              hipStream_t stream) {
    const float* x   = (const float*)d_in[0];
    const int*   src = (const int*)d_in[1];
    const int*   dst = (const int*)d_in[2];
    const float* W1  = (const float*)d_in[3];
    const float* b1  = (const float*)d_in[4];
    const float* W2  = (const float*)d_in[5];
    const float* b2  = (const float*)d_in[6];
    float* out = (float*)d_out;

    const int N = in_sizes[0] / 128;
    const int E = in_sizes[1];

    // workspace layout (4-byte units):
    int*   bucket_cursor  = (int*)d_ws;            // 512 (the only memset)
    int*   bucket_cnt_part= bucket_cursor + 512;   // BDST*512 (atomic-free slices)
    int*   bucket_ptr     = bucket_cnt_part + BDST * NBUCK; // 513
    int*   row_ptr        = bucket_ptr + 513;      // N+1 (sentinel row_ptr[N]=E)
    float* norm_src       = (float*)(row_ptr + N + 1); // N
    float* norm_dst       = norm_src + N;          // N
    // t region: 256B-aligned (misalignment doubles gather FETCH).
    long long toff = (3LL * N + 512 + BDST * NBUCK + 514 + 63) & ~63LL;
    float* tbase    = (float*)d_ws + toff;         // N*32 floats (t_h = N*64 fp16; binned = E*8 B)
    float* h        = tbase + (long long)N * 32;   // N*64 fp32
    int*   csr      = (int*)(h + (long long)N * D); // E
    __half* t_h = (__half*)tbase;                  // interleaved [N x 64] fp16
    unsigned long long* binned = (unsigned long long*)tbase;  // dead before gemm1
    // hist staging aliases h (dead until k_agg layer 1):
    // tiled layout ceil(wlen/16) tiles * 1024 words * 4B = 6.4 MB <= 25.6 MB
    unsigned* hstage = (unsigned*)h;

    const int NB = (N + 255) / 256;                // buckets used (391)
    const int NBK = (E + EPB - 1) / EPB;

    hipMemsetAsync(bucket_cursor, 0, 512 * sizeof(int), stream);

    k_hist<<<BDST + SRC_BLOCKS, 1024, 0, stream>>>(src, dst, hstage, bucket_cnt_part, E, N);
    k_scanB<<<1, 512, 0, stream>>>(bucket_cnt_part, bucket_ptr, row_ptr, N, E);
    k_bin<<<NBK, 256, 0, stream>>>(src, dst, bucket_ptr, bucket_cursor, binned, E);
    k_bsort<<<NB, 256, 0, stream>>>(binned, bucket_ptr, hstage, csr, row_ptr,
                                    norm_src, norm_dst, N);

    // layer 1: t = (x W1) * norm_src ; h = relu(agg * norm_dst + b1)
    k_gemm_mfma<128><<<(N + 63) / 64, 256, 0, stream>>>(x, W1, norm_src, t_h, N);
    k_agg<<<(N + 7) / 8, 256, 0, stream>>>(row_ptr, csr, t_h, norm_dst, b1, h, N, 1);

    // layer 2: t = (h W2) * norm_src ; out = agg * norm_dst + b2
    k_gemm_mfma<64><<<(N + 63) / 64, 256, 0, stream>>>(h, W2, norm_src, t_h, N);
    k_agg<<<(N + 7) / 8, 256, 0, stream>>>(row_ptr, csr, t_h, norm_dst, b2, out, N, 0);
}